// Round 5
// baseline (116.624 us; speedup 1.0000x reference)
//
#include <hip/hip_runtime.h>

// Problem constants (from reference): B=8, C=256, O=8, H=W=64, G=8
#define BB   8
#define CC   256
#define OO   8
#define GG   8
#define HW   4096        // 64*64
#define CPG  32          // C / G

typedef float f32x4_t __attribute__((ext_vector_type(4)));

// f32 -> bf16 bits (round-to-nearest-even), result in low 16 bits
static __device__ __forceinline__ unsigned f2bf_u(float f) {
    unsigned u = __float_as_uint(f);
    u += 0x7FFFu + ((u >> 16) & 1u);
    return u >> 16;
}
static __device__ __forceinline__ float bflo(unsigned u) {   // low bf16 -> f32
    return __uint_as_float(u << 16);
}
static __device__ __forceinline__ float bfhi(unsigned u) {   // high bf16 -> f32
    return __uint_as_float(u & 0xFFFF0000u);
}

// Block: 256 threads, each owns 4 consecutive hw elements (float4).
// - i1 = (i0+1)&7 always, so LDS stores the PACKED bf16 pair
//   (x[o], x[(o+1)&7]) per (j,o): one ds_read_b32 yields both lerp endpoints
//   -> 64 LDS ops/thread. Transposed private-column layout (no barrier),
//   bank = tid&31 -> free 2-way wave64 aliasing.
// - XCD swizzle: wg = (bid&7)*1024 + (bid>>3). Each XCD exclusively owns
//   4 (b,tile) groups -> every offset segment (32 KB, reused by 32 channel
//   blocks) is resident in exactly ONE XCD's L2 -> no cross-XCD refetch.
// - x loads + out stores nontemporal: zero-reuse streams stay out of L2/L3,
//   preserving them for offset (logical offset reads = 268 MB vs 8.4 MB
//   compulsory -> cache hit rate on offset is the whole ballgame).
__global__ __launch_bounds__(256, 5) void deo_kernel(const float* __restrict__ x,
                                                     const float* __restrict__ off,
                                                     float* __restrict__ out) {
    __shared__ unsigned lds[4 * OO * 256];   // 32 KB -> 5 blocks/CU

    const int tid = threadIdx.x;
    const int bid = blockIdx.x;

    // bijective XCD swizzle (8192 blocks, 8 XCDs, round-robin bid%8 -> XCD)
    const int wg = (bid & 7) * 1024 + (bid >> 3);

    const int c    = wg & 255;         // fastest: channels share offsets (L2)
    const int bt   = wg >> 8;
    const int tile = bt & 3;           // which 1024-elem hw tile
    const int b    = bt >> 2;
    const int g    = c >> 5;           // c / CPG

    const int hw0 = tile * 1024 + tid * 4;

    const float* xp = x   + ((size_t)(b * CC + c)) * (OO * HW) + hw0;
    const float* op = off + ((size_t)(b * GG + g)) * (OO * HW) + hw0;
    float*       yp = out + ((size_t)(b * CC + c)) * (OO * HW) + hw0;

    // ---- load all 8 orientations (nontemporal: x is a zero-reuse stream) ----
    f32x4_t xv[OO];
#pragma unroll
    for (int o = 0; o < OO; ++o)
        xv[o] = __builtin_nontemporal_load((const f32x4_t*)(xp + o * HW));

    // ---- convert once, stage packed neighbor-pairs ----
    unsigned h[OO][4];
#pragma unroll
    for (int o = 0; o < OO; ++o) {
        h[o][0] = f2bf_u(xv[o].x);
        h[o][1] = f2bf_u(xv[o].y);
        h[o][2] = f2bf_u(xv[o].z);
        h[o][3] = f2bf_u(xv[o].w);
    }
#pragma unroll
    for (int o = 0; o < OO; ++o) {
        const int on = (o + 1) & 7;
#pragma unroll
        for (int j = 0; j < 4; ++j) {
            lds[(j * OO + o) * 256 + tid] = h[o][j] | (h[on][j] << 16);
        }
    }
    // no barrier: private-column access pattern

    // ---- interpolate and store ----
    auto interp = [&](float offv, int o, int j) -> float {
        const float pv = (float)o + offv;
        const float p0 = floorf(pv);
        const float w1 = pv - p0;
        const int i0 = ((int)p0) & 7;        // cyclic wrap
        const unsigned u = lds[(j * OO + i0) * 256 + tid];
        const float a  = bflo(u);            // x[i0]
        const float bb = bfhi(u);            // x[(i0+1)&7]
        return fmaf(w1, bb - a, a);
    };

#pragma unroll
    for (int o = 0; o < OO; ++o) {
        const float4 w = *(const float4*)(op + o * HW);
        f32x4_t r;
        r.x = interp(w.x, o, 0);
        r.y = interp(w.y, o, 1);
        r.z = interp(w.z, o, 2);
        r.w = interp(w.w, o, 3);
        __builtin_nontemporal_store(r, (f32x4_t*)(yp + o * HW));
    }
}

extern "C" void kernel_launch(void* const* d_in, const int* in_sizes, int n_in,
                              void* d_out, int out_size, void* d_ws, size_t ws_size,
                              hipStream_t stream) {
    const float* x   = (const float*)d_in[0];
    const float* off = (const float*)d_in[1];
    float*       out = (float*)d_out;

    const int blocks = BB * (HW / 1024) * CC;   // 8192
    deo_kernel<<<blocks, 256, 0, stream>>>(x, off, out);
}

// Round 6
// 93.515 us; speedup vs baseline: 1.2471x; 1.2471x over previous
//
#include <hip/hip_runtime.h>

// Problem constants (from reference): B=8, C=256, O=8, H=W=64, G=8
#define BB   8
#define CC   256
#define OO   8
#define GG   8
#define HW   4096        // 64*64
#define CPG  32          // C / G

typedef float f32x4_t __attribute__((ext_vector_type(4)));

// f32 -> bf16 bits (round-to-nearest-even), result in low 16 bits
static __device__ __forceinline__ unsigned f2bf_u(float f) {
    unsigned u = __float_as_uint(f);
    u += 0x7FFFu + ((u >> 16) & 1u);
    return u >> 16;
}
static __device__ __forceinline__ float bflo(unsigned u) {   // low bf16 -> f32
    return __uint_as_float(u << 16);
}
static __device__ __forceinline__ float bfhi(unsigned u) {   // high bf16 -> f32
    return __uint_as_float(u & 0xFFFF0000u);
}

// ROUND-4 CONFIG (best: 93.6 us). Round-5's XCD swizzle + nt x-loads both
// reverted: L3 already absorbs cross-XCD offset re-reads (8.4 MB working
// set), so the swizzle had no upside and scattering the device-wide stream
// into 8 separated address ranges regressed 23 us.
//
// Block: 256 threads, each owns 4 consecutive hw elements (float4).
// - i1 = (i0+1)&7 always, so LDS stores the PACKED bf16 pair
//   (x[o], x[(o+1)&7]) per (j,o): one ds_read_b32 yields both lerp
//   endpoints -> 64 LDS ops/thread. Transposed private-column layout
//   (no barrier), bank = tid&31 -> free 2-way wave64 aliasing.
// - out stores nontemporal (zero-reuse stream, keep L2/L3 for offset).
__global__ __launch_bounds__(256, 5) void deo_kernel(const float* __restrict__ x,
                                                     const float* __restrict__ off,
                                                     float* __restrict__ out) {
    __shared__ unsigned lds[4 * OO * 256];   // 32 KB -> 5 blocks/CU

    const int tid = threadIdx.x;
    const int bid = blockIdx.x;

    const int c    = bid & 255;        // fastest: channels share offsets (L2/L3)
    const int bt   = bid >> 8;
    const int tile = bt & 3;           // which 1024-elem hw tile
    const int b    = bt >> 2;
    const int g    = c >> 5;           // c / CPG

    const int hw0 = tile * 1024 + tid * 4;

    const float* xp = x   + ((size_t)(b * CC + c)) * (OO * HW) + hw0;
    const float* op = off + ((size_t)(b * GG + g)) * (OO * HW) + hw0;
    float*       yp = out + ((size_t)(b * CC + c)) * (OO * HW) + hw0;

    // ---- load all 8 orientations ----
    float4 xv[OO];
#pragma unroll
    for (int o = 0; o < OO; ++o) xv[o] = *(const float4*)(xp + o * HW);

    // ---- convert once, stage packed neighbor-pairs ----
    unsigned h[OO][4];
#pragma unroll
    for (int o = 0; o < OO; ++o) {
        h[o][0] = f2bf_u(xv[o].x);
        h[o][1] = f2bf_u(xv[o].y);
        h[o][2] = f2bf_u(xv[o].z);
        h[o][3] = f2bf_u(xv[o].w);
    }
#pragma unroll
    for (int o = 0; o < OO; ++o) {
        const int on = (o + 1) & 7;
#pragma unroll
        for (int j = 0; j < 4; ++j) {
            lds[(j * OO + o) * 256 + tid] = h[o][j] | (h[on][j] << 16);
        }
    }
    // no barrier: private-column access pattern

    // ---- interpolate and store ----
    auto interp = [&](float offv, int o, int j) -> float {
        const float pv = (float)o + offv;
        const float p0 = floorf(pv);
        const float w1 = pv - p0;
        const int i0 = ((int)p0) & 7;        // cyclic wrap
        const unsigned u = lds[(j * OO + i0) * 256 + tid];
        const float a  = bflo(u);            // x[i0]
        const float bb = bfhi(u);            // x[(i0+1)&7]
        return fmaf(w1, bb - a, a);
    };

#pragma unroll
    for (int o = 0; o < OO; ++o) {
        const float4 w = *(const float4*)(op + o * HW);
        f32x4_t r;
        r.x = interp(w.x, o, 0);
        r.y = interp(w.y, o, 1);
        r.z = interp(w.z, o, 2);
        r.w = interp(w.w, o, 3);
        __builtin_nontemporal_store(r, (f32x4_t*)(yp + o * HW));
    }
}

extern "C" void kernel_launch(void* const* d_in, const int* in_sizes, int n_in,
                              void* d_out, int out_size, void* d_ws, size_t ws_size,
                              hipStream_t stream) {
    const float* x   = (const float*)d_in[0];
    const float* off = (const float*)d_in[1];
    float*       out = (float*)d_out;

    const int blocks = BB * (HW / 1024) * CC;   // 8192
    deo_kernel<<<blocks, 256, 0, stream>>>(x, off, out);
}

// Round 7
// 93.303 us; speedup vs baseline: 1.2500x; 1.0023x over previous
//
#include <hip/hip_runtime.h>

// Problem constants (from reference): B=8, C=256, O=8, H=W=64, G=8
#define BB   8
#define CC   256
#define OO   8
#define GG   8
#define HW   4096        // 64*64
#define NCH  4           // channels per block (same group -> shared offsets)

typedef float f32x4_t __attribute__((ext_vector_type(4)));

// f32 -> bf16 bits (round-to-nearest-even), result in low 16 bits
static __device__ __forceinline__ unsigned f2bf_u(float f) {
    unsigned u = __float_as_uint(f);
    u += 0x7FFFu + ((u >> 16) & 1u);
    return u >> 16;
}
static __device__ __forceinline__ float bflo(unsigned u) {   // low bf16 -> f32
    return __uint_as_float(u << 16);
}
static __device__ __forceinline__ float bfhi(unsigned u) {   // high bf16 -> f32
    return __uint_as_float(u & 0xFFFF0000u);
}

// Round-4 core (packed bf16-pair LDS, private-column, nt stores) + NCH=4
// channel amortization: per-thread (i0,w1) for all 32 (o,j) elements is
// computed ONCE and packed into one u32 each:
//   pw = lds_word_idx (13 bits) | bf16(w1) << 16
// then reused across 4 channels of the same group. Offset logical traffic
// drops 268 MB -> 67 MB (L3 contention relief); offset VALU amortized 4x.
// LDS reused across channels without barriers: same-thread same-address
// ds ops are in-order, and columns are thread-private.
__global__ __launch_bounds__(256, 4) void deo_kernel(const float* __restrict__ x,
                                                     const float* __restrict__ off,
                                                     float* __restrict__ out) {
    __shared__ unsigned lds[4 * OO * 256];   // 32 KB

    const int tid = threadIdx.x;
    const int bid = blockIdx.x;

    // bid = ((b*4 + tile)*8 + g)*8 + chunk  (chunk fastest: 8 consecutive
    // blocks share one offset tile in L2)
    const int chunk = bid & 7;
    const int g     = (bid >> 3) & 7;
    const int tile  = (bid >> 6) & 3;
    const int b     = bid >> 8;

    const int c0  = g * 32 + chunk * NCH;
    const int hw0 = tile * 1024 + tid * 4;

    const float* op = off + ((size_t)(b * GG + g)) * (OO * HW) + hw0;

    // ---- precompute packed (lds word idx | bf16 w1) per element ----
    unsigned pw[OO][4];
#pragma unroll
    for (int o = 0; o < OO; ++o) {
        const float4 w = *(const float4*)(op + o * HW);
        const float wv[4] = {w.x, w.y, w.z, w.w};
#pragma unroll
        for (int j = 0; j < 4; ++j) {
            const float pv = (float)o + wv[j];
            const float p0 = floorf(pv);
            const float w1 = pv - p0;
            const int   i0 = ((int)p0) & 7;               // cyclic wrap
            const unsigned idx = (unsigned)((j * OO + i0) * 256 + tid);
            pw[o][j] = idx | (f2bf_u(w1) << 16);
        }
    }

    // ---- channel loop (not unrolled: keep VGPR peak low) ----
#pragma unroll 1
    for (int ch = 0; ch < NCH; ++ch) {
        const size_t base = ((size_t)(b * CC + c0 + ch)) * (OO * HW) + hw0;
        const float* xp = x   + base;
        float*       yp = out + base;

        float4 xv[OO];
#pragma unroll
        for (int o = 0; o < OO; ++o) xv[o] = *(const float4*)(xp + o * HW);

        unsigned h[OO][4];
#pragma unroll
        for (int o = 0; o < OO; ++o) {
            h[o][0] = f2bf_u(xv[o].x);
            h[o][1] = f2bf_u(xv[o].y);
            h[o][2] = f2bf_u(xv[o].z);
            h[o][3] = f2bf_u(xv[o].w);
        }
#pragma unroll
        for (int o = 0; o < OO; ++o) {
            const int on = (o + 1) & 7;
#pragma unroll
            for (int j = 0; j < 4; ++j)
                lds[(j * OO + o) * 256 + tid] = h[o][j] | (h[on][j] << 16);
        }
        // no barrier: private-column access pattern

#pragma unroll
        for (int o = 0; o < OO; ++o) {
            f32x4_t r;
#pragma unroll
            for (int j = 0; j < 4; ++j) {
                const unsigned pwv = pw[o][j];
                const unsigned u   = lds[pwv & 0xFFFFu];
                const float w1 = bfhi(pwv);               // bf16 weight
                const float a  = bflo(u);                 // x[i0]
                const float bb = bfhi(u);                 // x[(i0+1)&7]
                r[j] = fmaf(w1, bb - a, a);
            }
            __builtin_nontemporal_store(r, (f32x4_t*)(yp + o * HW));
        }
    }
}

extern "C" void kernel_launch(void* const* d_in, const int* in_sizes, int n_in,
                              void* d_out, int out_size, void* d_ws, size_t ws_size,
                              hipStream_t stream) {
    const float* x   = (const float*)d_in[0];
    const float* off = (const float*)d_in[1];
    float*       out = (float*)d_out;

    const int blocks = BB * 4 * GG * (32 / NCH);   // 2048
    deo_kernel<<<blocks, 256, 0, stream>>>(x, off, out);
}